// Round 1
// baseline (658.775 us; speedup 1.0000x reference)
//
#include <hip/hip_runtime.h>
#include <math.h>

#define L_SEQ 32768
#define H_DIM 512
#define P_DIM 256
#define CHUNK 128
#define NCHUNK (L_SEQ / CHUNK)   // 256

// ---------------------------------------------------------------------------
// GEMM1: G[l,p] = sum_h U[l,h] * B[p,h]   (complex B -> two output planes)
// Tiles: BM=64 (l), BN=64 (p), BK=16 (h). 256 threads, 4x4 microtile.
// Both operands are K-contiguous (row-major with K inner) -> float4 loads.
// ---------------------------------------------------------------------------
__global__ __launch_bounds__(256) void gemm1_kernel(
    const float* __restrict__ U,    // L x H
    const float* __restrict__ Bre,  // P x H
    const float* __restrict__ Bim,  // P x H
    float* __restrict__ Gre,        // L x P
    float* __restrict__ Gim)        // L x P
{
    const int tid = threadIdx.x;
    const int bm = blockIdx.x;   // over L/64
    const int bn = blockIdx.y;   // over P/64

    __shared__ float As [16 * 68];
    __shared__ float Bsr[16 * 68];
    __shared__ float Bsi[16 * 68];

    float accre[4][4] = {{0.f}};
    float accim[4][4] = {{0.f}};

    const int tx = tid & 15;         // 0..15 -> n microtile
    const int ty = tid >> 4;         // 0..15 -> m microtile
    const int ldrow = tid >> 2;      // 0..63
    const int ldk4  = (tid & 3) << 2; // 0,4,8,12

    const size_t arow = (size_t)(bm * 64 + ldrow) * H_DIM;
    const size_t brow = (size_t)(bn * 64 + ldrow) * H_DIM;

    for (int kt = 0; kt < H_DIM; kt += 16) {
        float4 a4  = *(const float4*)&U  [arow + kt + ldk4];
        float4 br4 = *(const float4*)&Bre[brow + kt + ldk4];
        float4 bi4 = *(const float4*)&Bim[brow + kt + ldk4];
        __syncthreads();
        As [(ldk4 + 0) * 68 + ldrow] = a4.x;
        As [(ldk4 + 1) * 68 + ldrow] = a4.y;
        As [(ldk4 + 2) * 68 + ldrow] = a4.z;
        As [(ldk4 + 3) * 68 + ldrow] = a4.w;
        Bsr[(ldk4 + 0) * 68 + ldrow] = br4.x;
        Bsr[(ldk4 + 1) * 68 + ldrow] = br4.y;
        Bsr[(ldk4 + 2) * 68 + ldrow] = br4.z;
        Bsr[(ldk4 + 3) * 68 + ldrow] = br4.w;
        Bsi[(ldk4 + 0) * 68 + ldrow] = bi4.x;
        Bsi[(ldk4 + 1) * 68 + ldrow] = bi4.y;
        Bsi[(ldk4 + 2) * 68 + ldrow] = bi4.z;
        Bsi[(ldk4 + 3) * 68 + ldrow] = bi4.w;
        __syncthreads();

        #pragma unroll
        for (int k = 0; k < 16; ++k) {
            float4 av  = *(float4*)&As [k * 68 + ty * 4];
            float4 bvr = *(float4*)&Bsr[k * 68 + tx * 4];
            float4 bvi = *(float4*)&Bsi[k * 68 + tx * 4];
            float a[4]  = {av.x, av.y, av.z, av.w};
            float br[4] = {bvr.x, bvr.y, bvr.z, bvr.w};
            float bi[4] = {bvi.x, bvi.y, bvi.z, bvi.w};
            #pragma unroll
            for (int i = 0; i < 4; ++i) {
                #pragma unroll
                for (int j = 0; j < 4; ++j) {
                    accre[i][j] = fmaf(a[i], br[j], accre[i][j]);
                    accim[i][j] = fmaf(a[i], bi[j], accim[i][j]);
                }
            }
        }
    }

    #pragma unroll
    for (int i = 0; i < 4; ++i) {
        const int l = bm * 64 + ty * 4 + i;
        #pragma unroll
        for (int j = 0; j < 4; ++j) {
            const int p = bn * 64 + tx * 4 + j;
            Gre[(size_t)l * P_DIM + p] = accre[i][j];
            Gim[(size_t)l * P_DIM + p] = accim[i][j];
        }
    }
}

// ---------------------------------------------------------------------------
// Chunked scan over x_l = a_l * x_{l-1} + b_l  (complex, per channel p).
// a_l = exp(lambda * step * dt_l), b_l = (a_l - 1)/lambda * G[l,p].
// WRITE_X==0: compute chunk aggregates (A_prod, B_agg).
// WRITE_X==1: start from carry, write x in-place over G.
// ---------------------------------------------------------------------------
template <int WRITE_X>
__global__ __launch_bounds__(256) void scan_chunk_kernel(
    const float* __restrict__ dts,      // L
    const float* __restrict__ Lre_g,
    const float* __restrict__ Lim_g,
    const float* __restrict__ logstep,
    float* __restrict__ Gre,            // L x P (in: Bu pre-gamma; out pass2: x)
    float* __restrict__ Gim,
    float* __restrict__ Aagg_re, float* __restrict__ Aagg_im,
    float* __restrict__ Bagg_re, float* __restrict__ Bagg_im,
    const float* __restrict__ carry_re, const float* __restrict__ carry_im)
{
    const int p = threadIdx.x;   // 0..255
    const int c = blockIdx.x;    // chunk

    const float lre = Lre_g[p];
    const float lim = Lim_g[p];
    const float stp = expf(logstep[p]);
    const float inv_den = 1.0f / (lre * lre + lim * lim);

    float Are = 1.0f, Aim = 0.0f;
    float xre, xim;
    if (WRITE_X) {
        xre = carry_re[c * P_DIM + p];
        xim = carry_im[c * P_DIM + p];
    } else {
        xre = 0.0f; xim = 0.0f;
    }

    const int base = c * CHUNK;
    for (int i = 0; i < CHUNK; ++i) {
        const int l = base + i;
        const float d = stp * dts[l];
        const float er = expf(lre * d);
        float sn, cs;
        sincosf(lim * d, &sn, &cs);
        const float are = er * cs;
        const float aim = er * sn;
        // gamma = (a - 1) * conj(lambda) / |lambda|^2
        const float am1 = are - 1.0f;
        const float gr = (am1 * lre + aim * lim) * inv_den;
        const float gi = (aim * lre - am1 * lim) * inv_den;

        const size_t idx = (size_t)l * P_DIM + p;
        const float ure = Gre[idx];
        const float uim = Gim[idx];
        const float bre = gr * ure - gi * uim;
        const float bim = gr * uim + gi * ure;

        const float nxre = are * xre - aim * xim + bre;
        const float nxim = are * xim + aim * xre + bim;
        xre = nxre; xim = nxim;

        if (WRITE_X) {
            Gre[idx] = xre;
            Gim[idx] = xim;
        } else {
            const float nAre = are * Are - aim * Aim;
            const float nAim = are * Aim + aim * Are;
            Are = nAre; Aim = nAim;
        }
    }

    if (!WRITE_X) {
        Aagg_re[c * P_DIM + p] = Are;
        Aagg_im[c * P_DIM + p] = Aim;
        Bagg_re[c * P_DIM + p] = xre;
        Bagg_im[c * P_DIM + p] = xim;
    }
}

// ---------------------------------------------------------------------------
// Carry scan across chunks (exclusive): carry[c] = A[c-1]*carry[c-1] + B[c-1]
// One thread per channel p; NCHUNK sequential steps.
// ---------------------------------------------------------------------------
__global__ __launch_bounds__(256) void carry_kernel(
    const float* __restrict__ Aagg_re, const float* __restrict__ Aagg_im,
    const float* __restrict__ Bagg_re, const float* __restrict__ Bagg_im,
    float* __restrict__ carry_re, float* __restrict__ carry_im)
{
    const int p = threadIdx.x;
    float cre = 0.0f, cim = 0.0f;
    for (int c = 0; c < NCHUNK; ++c) {
        carry_re[c * P_DIM + p] = cre;
        carry_im[c * P_DIM + p] = cim;
        const float are = Aagg_re[c * P_DIM + p];
        const float aim = Aagg_im[c * P_DIM + p];
        const float bre = Bagg_re[c * P_DIM + p];
        const float bim = Bagg_im[c * P_DIM + p];
        const float nre = are * cre - aim * cim + bre;
        const float nim = are * cim + aim * cre + bim;
        cre = nre; cim = nim;
    }
}

// ---------------------------------------------------------------------------
// GEMM2: out[l,h] = 2*(sum_p Xre[l,p]*Cre[h,p] - Xim[l,p]*Cim[h,p]) + D[h]*U[l,h]
// ---------------------------------------------------------------------------
__global__ __launch_bounds__(256) void gemm2_kernel(
    const float* __restrict__ Xre,  // L x P
    const float* __restrict__ Xim,  // L x P
    const float* __restrict__ Cre,  // H x P
    const float* __restrict__ Cim,  // H x P
    const float* __restrict__ U,    // L x H
    const float* __restrict__ Dv,   // H
    float* __restrict__ Out)        // L x H
{
    const int tid = threadIdx.x;
    const int bm = blockIdx.x;   // over L/64
    const int bn = blockIdx.y;   // over H/64

    __shared__ float Ar[16 * 68];
    __shared__ float Ai[16 * 68];
    __shared__ float Br[16 * 68];
    __shared__ float Bi[16 * 68];

    float acc[4][4] = {{0.f}};

    const int tx = tid & 15;
    const int ty = tid >> 4;
    const int ldrow = tid >> 2;
    const int ldk4  = (tid & 3) << 2;

    const size_t arow = (size_t)(bm * 64 + ldrow) * P_DIM;
    const size_t brow = (size_t)(bn * 64 + ldrow) * P_DIM;

    for (int kt = 0; kt < P_DIM; kt += 16) {
        float4 ar4 = *(const float4*)&Xre[arow + kt + ldk4];
        float4 ai4 = *(const float4*)&Xim[arow + kt + ldk4];
        float4 br4 = *(const float4*)&Cre[brow + kt + ldk4];
        float4 bi4 = *(const float4*)&Cim[brow + kt + ldk4];
        __syncthreads();
        Ar[(ldk4 + 0) * 68 + ldrow] = ar4.x;
        Ar[(ldk4 + 1) * 68 + ldrow] = ar4.y;
        Ar[(ldk4 + 2) * 68 + ldrow] = ar4.z;
        Ar[(ldk4 + 3) * 68 + ldrow] = ar4.w;
        Ai[(ldk4 + 0) * 68 + ldrow] = ai4.x;
        Ai[(ldk4 + 1) * 68 + ldrow] = ai4.y;
        Ai[(ldk4 + 2) * 68 + ldrow] = ai4.z;
        Ai[(ldk4 + 3) * 68 + ldrow] = ai4.w;
        Br[(ldk4 + 0) * 68 + ldrow] = br4.x;
        Br[(ldk4 + 1) * 68 + ldrow] = br4.y;
        Br[(ldk4 + 2) * 68 + ldrow] = br4.z;
        Br[(ldk4 + 3) * 68 + ldrow] = br4.w;
        Bi[(ldk4 + 0) * 68 + ldrow] = bi4.x;
        Bi[(ldk4 + 1) * 68 + ldrow] = bi4.y;
        Bi[(ldk4 + 2) * 68 + ldrow] = bi4.z;
        Bi[(ldk4 + 3) * 68 + ldrow] = bi4.w;
        __syncthreads();

        #pragma unroll
        for (int k = 0; k < 16; ++k) {
            float4 avr = *(float4*)&Ar[k * 68 + ty * 4];
            float4 avi = *(float4*)&Ai[k * 68 + ty * 4];
            float4 bvr = *(float4*)&Br[k * 68 + tx * 4];
            float4 bvi = *(float4*)&Bi[k * 68 + tx * 4];
            float xr[4] = {avr.x, avr.y, avr.z, avr.w};
            float xi[4] = {avi.x, avi.y, avi.z, avi.w};
            float cr[4] = {bvr.x, bvr.y, bvr.z, bvr.w};
            float ci[4] = {bvi.x, bvi.y, bvi.z, bvi.w};
            #pragma unroll
            for (int i = 0; i < 4; ++i) {
                #pragma unroll
                for (int j = 0; j < 4; ++j) {
                    acc[i][j] = fmaf(xr[i], cr[j], acc[i][j]);
                    acc[i][j] = fmaf(-xi[i], ci[j], acc[i][j]);
                }
            }
        }
    }

    #pragma unroll
    for (int i = 0; i < 4; ++i) {
        const int l = bm * 64 + ty * 4 + i;
        #pragma unroll
        for (int j = 0; j < 4; ++j) {
            const int h = bn * 64 + tx * 4 + j;
            const size_t o = (size_t)l * H_DIM + h;
            Out[o] = 2.0f * acc[i][j] + Dv[h] * U[o];
        }
    }
}

extern "C" void kernel_launch(void* const* d_in, const int* in_sizes, int n_in,
                              void* d_out, int out_size, void* d_ws, size_t ws_size,
                              hipStream_t stream) {
    const float* U       = (const float*)d_in[0];
    const float* dts     = (const float*)d_in[1];
    const float* Lre     = (const float*)d_in[2];
    const float* Lim     = (const float*)d_in[3];
    const float* Bre     = (const float*)d_in[4];
    const float* Bim     = (const float*)d_in[5];
    const float* Cre     = (const float*)d_in[6];
    const float* Cim     = (const float*)d_in[7];
    const float* Dv      = (const float*)d_in[8];
    const float* logstep = (const float*)d_in[9];
    float* out = (float*)d_out;

    float* ws = (float*)d_ws;
    const size_t LP = (size_t)L_SEQ * P_DIM;       // 8,388,608
    const size_t CP = (size_t)NCHUNK * P_DIM;      // 65,536
    float* Gre      = ws;
    float* Gim      = Gre + LP;
    float* Aagg_re  = Gim + LP;
    float* Aagg_im  = Aagg_re + CP;
    float* Bagg_re  = Aagg_im + CP;
    float* Bagg_im  = Bagg_re + CP;
    float* carry_re = Bagg_im + CP;
    float* carry_im = carry_re + CP;

    dim3 g1(L_SEQ / 64, P_DIM / 64);
    gemm1_kernel<<<g1, 256, 0, stream>>>(U, Bre, Bim, Gre, Gim);

    scan_chunk_kernel<0><<<NCHUNK, 256, 0, stream>>>(
        dts, Lre, Lim, logstep, Gre, Gim,
        Aagg_re, Aagg_im, Bagg_re, Bagg_im, nullptr, nullptr);

    carry_kernel<<<1, P_DIM, 0, stream>>>(
        Aagg_re, Aagg_im, Bagg_re, Bagg_im, carry_re, carry_im);

    scan_chunk_kernel<1><<<NCHUNK, 256, 0, stream>>>(
        dts, Lre, Lim, logstep, Gre, Gim,
        nullptr, nullptr, nullptr, nullptr, carry_re, carry_im);

    dim3 g2(L_SEQ / 64, H_DIM / 64);
    gemm2_kernel<<<g2, 256, 0, stream>>>(Gre, Gim, Cre, Cim, U, Dv, out);
}

// Round 2
// 290.934 us; speedup vs baseline: 2.2643x; 2.2643x over previous
//
#include <hip/hip_runtime.h>
#include <math.h>

#define L_SEQ 32768
#define H_DIM 512
#define P_DIM 256
#define K_DIM 512            // both GEMMs: K = 512
#define CHUNK 64
#define NCHUNK (L_SEQ / CHUNK)   // 512

typedef __bf16 bf16x8 __attribute__((ext_vector_type(8)));
typedef __bf16 bf16x4 __attribute__((ext_vector_type(4)));
typedef float floatx4 __attribute__((ext_vector_type(4)));

__device__ __forceinline__ void gll16(const void* g, void* l) {
    __builtin_amdgcn_global_load_lds(
        (__attribute__((address_space(1))) void*)(g),
        (__attribute__((address_space(3))) void*)(l), 16, 0, 0);
}

// ---------------------------------------------------------------------------
// fp32 -> bf16 conversion, 4 elems/thread
// ---------------------------------------------------------------------------
__global__ __launch_bounds__(256) void f2bf_kernel(
    const float* __restrict__ in, __bf16* __restrict__ out)
{
    const int i = blockIdx.x * 256 + threadIdx.x;
    float4 v = ((const float4*)in)[i];
    bf16x4 o;
    o.x = (__bf16)v.x; o.y = (__bf16)v.y; o.z = (__bf16)v.z; o.w = (__bf16)v.w;
    ((bf16x4*)out)[i] = o;
}

// C2[h, p] = Cre[h,p]; C2[h, 256+p] = -Cim[h,p]   (H x 512 bf16)
__global__ __launch_bounds__(256) void build_c2_kernel(
    const float* __restrict__ Cre, const float* __restrict__ Cim,
    __bf16* __restrict__ C2)
{
    const int h = blockIdx.x;
    const int p = threadIdx.x;
    C2[h * 512 + p]       = (__bf16)Cre[h * P_DIM + p];
    C2[h * 512 + 256 + p] = (__bf16)(-Cim[h * P_DIM + p]);
}

// ---------------------------------------------------------------------------
// bf16 MFMA GEMM (m97 structure): Out[M,512] = A[M,512] * Bm[512,512]^T
// BM=BN=128, BK=32, 256 threads (4 waves, 2x2 of 64x64), 16x16x32 MFMA.
// EPI==0: store fp32.  EPI==1: out = 2*acc + D[col]*U[row,col].
// ---------------------------------------------------------------------------
template <int EPI>
__global__ __launch_bounds__(256) void mfma_gemm_kernel(
    const __bf16* __restrict__ A,    // M x 512, K-contiguous
    const __bf16* __restrict__ Bm,   // 512 x 512, K-contiguous
    float* __restrict__ Out,         // M x 512
    const float* __restrict__ U,     // EPI==1 only
    const float* __restrict__ Dv)    // EPI==1 only
{
    __shared__ __bf16 As[128 * 32];
    __shared__ __bf16 Bs[128 * 32];

    const int tid = threadIdx.x;
    const int w  = tid >> 6;
    const int ln = tid & 63;
    const int bm = blockIdx.x;
    const int bn = blockIdx.y;

    floatx4 acc[4][4];
    #pragma unroll
    for (int i = 0; i < 4; ++i)
        #pragma unroll
        for (int j = 0; j < 4; ++j)
            acc[i][j] = (floatx4){0.f, 0.f, 0.f, 0.f};

    // staging: per issue, wave w covers LDS bytes [w*1024, +1024) = rows w*16..+15
    const int lr = ln >> 2;            // row within wave's 16
    const int lce = (ln & 3) << 3;     // k-elem offset (0,8,16,24) = 16B chunks
    const size_t arow = (size_t)(bm * 128 + w * 16 + lr) * K_DIM;
    const size_t brow = (size_t)(bn * 128 + w * 16 + lr) * K_DIM;

    __bf16* lA0 = As + w * 512;          // byte w*1024
    __bf16* lA1 = As + 2048 + w * 512;   // byte 4096 + w*1024
    __bf16* lB0 = Bs + w * 512;
    __bf16* lB1 = Bs + 2048 + w * 512;

    // fragment read offsets
    const int wm = (w >> 1) * 64;
    const int wn = (w & 1) * 64;
    const int fr = ln & 15;
    const int fq = (ln >> 4) * 8;        // k-elem offset of this quad

    for (int kt = 0; kt < K_DIM; kt += 32) {
        __syncthreads();
        gll16(A  + arow + kt + lce,               lA0);
        gll16(A  + arow + (size_t)64 * K_DIM + kt + lce, lA1);
        gll16(Bm + brow + kt + lce,               lB0);
        gll16(Bm + brow + (size_t)64 * K_DIM + kt + lce, lB1);
        __syncthreads();

        bf16x8 a[4], b[4];
        #pragma unroll
        for (int mt = 0; mt < 4; ++mt)
            a[mt] = *(bf16x8*)&As[(wm + mt * 16 + fr) * 32 + fq];
        #pragma unroll
        for (int nt = 0; nt < 4; ++nt)
            b[nt] = *(bf16x8*)&Bs[(wn + nt * 16 + fr) * 32 + fq];

        #pragma unroll
        for (int mt = 0; mt < 4; ++mt)
            #pragma unroll
            for (int nt = 0; nt < 4; ++nt)
                acc[mt][nt] = __builtin_amdgcn_mfma_f32_16x16x32_bf16(
                    a[mt], b[nt], acc[mt][nt], 0, 0, 0);
    }

    // epilogue: C/D layout col=ln&15, row=(ln>>4)*4+reg
    const int rq = (ln >> 4) * 4;
    #pragma unroll
    for (int mt = 0; mt < 4; ++mt) {
        const int gro = bm * 128 + wm + mt * 16 + rq;
        #pragma unroll
        for (int nt = 0; nt < 4; ++nt) {
            const int gco = bn * 128 + wn + nt * 16 + (ln & 15);
            float dh = (EPI == 1) ? Dv[gco] : 0.f;
            #pragma unroll
            for (int r = 0; r < 4; ++r) {
                const size_t o = (size_t)(gro + r) * 512 + gco;
                if (EPI == 0) {
                    Out[o] = acc[mt][nt][r];
                } else {
                    Out[o] = 2.0f * acc[mt][nt][r] + dh * U[o];
                }
            }
        }
    }
}

// ---------------------------------------------------------------------------
// Chunked scan: x_l = a_l * x_{l-1} + b_l (complex per channel p).
// G2 layout: G2[l*512 + p] = Gre, G2[l*512 + 256 + p] = Gim.
// WRITE_X==0: chunk aggregates. WRITE_X==1: apply carry, emit bf16 X2.
// ---------------------------------------------------------------------------
template <int WRITE_X>
__global__ __launch_bounds__(256) void scan_chunk_kernel(
    const float* __restrict__ dts,
    const float* __restrict__ Lre_g, const float* __restrict__ Lim_g,
    const float* __restrict__ logstep,
    const float* __restrict__ G2,     // L x 512 fp32
    __bf16* __restrict__ X2,          // L x 512 bf16 (WRITE_X==1)
    float* __restrict__ Aagg_re, float* __restrict__ Aagg_im,
    float* __restrict__ Bagg_re, float* __restrict__ Bagg_im,
    const float* __restrict__ carry_re, const float* __restrict__ carry_im)
{
    const int p = threadIdx.x;
    const int c = blockIdx.x;

    const float lre = Lre_g[p];
    const float lim = Lim_g[p];
    const float stp = expf(logstep[p]);
    const float inv_den = 1.0f / (lre * lre + lim * lim);

    float Are = 1.0f, Aim = 0.0f;
    float xre, xim;
    if (WRITE_X) {
        xre = carry_re[c * P_DIM + p];
        xim = carry_im[c * P_DIM + p];
    } else {
        xre = 0.0f; xim = 0.0f;
    }

    const int base = c * CHUNK;
    for (int i = 0; i < CHUNK; ++i) {
        const int l = base + i;
        const float d = stp * dts[l];
        const float er = expf(lre * d);
        float sn, cs;
        __sincosf(lim * d, &sn, &cs);
        const float are = er * cs;
        const float aim = er * sn;
        const float am1 = are - 1.0f;
        const float gr = (am1 * lre + aim * lim) * inv_den;
        const float gi = (aim * lre - am1 * lim) * inv_den;

        const size_t idx = (size_t)l * 512 + p;
        const float ure = G2[idx];
        const float uim = G2[idx + 256];
        const float bre = gr * ure - gi * uim;
        const float bim = gr * uim + gi * ure;

        const float nxre = are * xre - aim * xim + bre;
        const float nxim = are * xim + aim * xre + bim;
        xre = nxre; xim = nxim;

        if (WRITE_X) {
            X2[idx]       = (__bf16)xre;
            X2[idx + 256] = (__bf16)xim;
        } else {
            const float nAre = are * Are - aim * Aim;
            const float nAim = are * Aim + aim * Are;
            Are = nAre; Aim = nAim;
        }
    }

    if (!WRITE_X) {
        Aagg_re[c * P_DIM + p] = Are;
        Aagg_im[c * P_DIM + p] = Aim;
        Bagg_re[c * P_DIM + p] = xre;
        Bagg_im[c * P_DIM + p] = xim;
    }
}

__global__ __launch_bounds__(256) void carry_kernel(
    const float* __restrict__ Aagg_re, const float* __restrict__ Aagg_im,
    const float* __restrict__ Bagg_re, const float* __restrict__ Bagg_im,
    float* __restrict__ carry_re, float* __restrict__ carry_im)
{
    const int p = threadIdx.x;
    float cre = 0.0f, cim = 0.0f;
    for (int c = 0; c < NCHUNK; ++c) {
        carry_re[c * P_DIM + p] = cre;
        carry_im[c * P_DIM + p] = cim;
        const float are = Aagg_re[c * P_DIM + p];
        const float aim = Aagg_im[c * P_DIM + p];
        const float bre = Bagg_re[c * P_DIM + p];
        const float bim = Bagg_im[c * P_DIM + p];
        const float nre = are * cre - aim * cim + bre;
        const float nim = are * cim + aim * cre + bim;
        cre = nre; cim = nim;
    }
}

extern "C" void kernel_launch(void* const* d_in, const int* in_sizes, int n_in,
                              void* d_out, int out_size, void* d_ws, size_t ws_size,
                              hipStream_t stream) {
    const float* U       = (const float*)d_in[0];
    const float* dts     = (const float*)d_in[1];
    const float* Lre     = (const float*)d_in[2];
    const float* Lim     = (const float*)d_in[3];
    const float* Bre     = (const float*)d_in[4];
    const float* Bim     = (const float*)d_in[5];
    const float* Cre     = (const float*)d_in[6];
    const float* Cim     = (const float*)d_in[7];
    const float* Dv      = (const float*)d_in[8];
    const float* logstep = (const float*)d_in[9];
    float* out = (float*)d_out;

    // workspace carve (bytes)
    char* ws = (char*)d_ws;
    __bf16* Ubf  = (__bf16*)ws;                         // L x 512 bf16 (32 MB)
    __bf16* X2   = Ubf;                                 // alias: Ubf dead after gemm1
    __bf16* B2   = (__bf16*)(ws + (size_t)L_SEQ * 512 * 2);            // 512x512 bf16
    __bf16* C2   = B2 + 512 * 512;                                     // 512x512 bf16
    float*  Aagg_re  = (float*)(C2 + 512 * 512);
    float*  Aagg_im  = Aagg_re + NCHUNK * P_DIM;
    float*  Bagg_re  = Aagg_im + NCHUNK * P_DIM;
    float*  Bagg_im  = Bagg_re + NCHUNK * P_DIM;
    float*  carry_re = Bagg_im + NCHUNK * P_DIM;
    float*  carry_im = carry_re + NCHUNK * P_DIM;

    // G2 (fp32 L x 512) lives in d_out until gemm2 overwrites it with the result
    float* G2 = out;

    // conversions
    f2bf_kernel<<<(L_SEQ * H_DIM) / 4 / 256, 256, 0, stream>>>(U, Ubf);
    f2bf_kernel<<<(P_DIM * H_DIM) / 4 / 256, 256, 0, stream>>>(Bre, B2);
    f2bf_kernel<<<(P_DIM * H_DIM) / 4 / 256, 256, 0, stream>>>(Bim, B2 + P_DIM * H_DIM);
    build_c2_kernel<<<H_DIM, 256, 0, stream>>>(Cre, Cim, C2);

    // GEMM1: G2 = Ubf * B2^T  (cols 0..255 = Re, 256..511 = Im)
    dim3 g1(L_SEQ / 128, 4);
    mfma_gemm_kernel<0><<<g1, 256, 0, stream>>>(Ubf, B2, G2, nullptr, nullptr);

    // scan
    scan_chunk_kernel<0><<<NCHUNK, 256, 0, stream>>>(
        dts, Lre, Lim, logstep, G2, nullptr,
        Aagg_re, Aagg_im, Bagg_re, Bagg_im, nullptr, nullptr);
    carry_kernel<<<1, P_DIM, 0, stream>>>(
        Aagg_re, Aagg_im, Bagg_re, Bagg_im, carry_re, carry_im);
    scan_chunk_kernel<1><<<NCHUNK, 256, 0, stream>>>(
        dts, Lre, Lim, logstep, G2, X2,
        nullptr, nullptr, nullptr, nullptr, carry_re, carry_im);

    // GEMM2: out = 2 * X2 * C2^T + D*u
    dim3 g2(L_SEQ / 128, 4);
    mfma_gemm_kernel<1><<<g2, 256, 0, stream>>>(X2, C2, out, U, Dv);
}

// Round 3
// 244.411 us; speedup vs baseline: 2.6954x; 1.1903x over previous
//
#include <hip/hip_runtime.h>
#include <math.h>

#define L_SEQ 32768
#define H_DIM 512
#define P_DIM 256
#define K_DIM 512            // both GEMMs: K = 512
#define CHUNK 32
#define NCHUNK (L_SEQ / CHUNK)   // 1024

typedef __bf16 bf16x8 __attribute__((ext_vector_type(8)));
typedef __bf16 bf16x4 __attribute__((ext_vector_type(4)));
typedef float floatx4 __attribute__((ext_vector_type(4)));

__device__ __forceinline__ void gll16(const void* g, void* l) {
    __builtin_amdgcn_global_load_lds(
        (__attribute__((address_space(1))) void*)(g),
        (__attribute__((address_space(3))) void*)(l), 16, 0, 0);
}

// ---------------------------------------------------------------------------
// fp32 -> bf16 conversion, 4 elems/thread
// ---------------------------------------------------------------------------
__global__ __launch_bounds__(256) void f2bf_kernel(
    const float* __restrict__ in, __bf16* __restrict__ out)
{
    const int i = blockIdx.x * 256 + threadIdx.x;
    float4 v = ((const float4*)in)[i];
    bf16x4 o;
    o.x = (__bf16)v.x; o.y = (__bf16)v.y; o.z = (__bf16)v.z; o.w = (__bf16)v.w;
    ((bf16x4*)out)[i] = o;
}

// C2[h, p] = Cre[h,p]; C2[h, 256+p] = -Cim[h,p]   (H x 512 bf16)
__global__ __launch_bounds__(256) void build_c2_kernel(
    const float* __restrict__ Cre, const float* __restrict__ Cim,
    __bf16* __restrict__ C2)
{
    const int h = blockIdx.x;
    const int p = threadIdx.x;
    C2[h * 512 + p]       = (__bf16)Cre[h * P_DIM + p];
    C2[h * 512 + 256 + p] = (__bf16)(-Cim[h * P_DIM + p]);
}

// ---------------------------------------------------------------------------
// bf16 MFMA GEMM (m97 structure): Out[M,512] = A[M,512] * Bm[512,512]^T
// BM=BN=128, BK=32, 256 threads (4 waves, 2x2 of 64x64), 16x16x32 MFMA.
// EPI==0: store fp32.  EPI==1: out = 2*acc + D[col]*U[row,col].
// ---------------------------------------------------------------------------
template <int EPI>
__global__ __launch_bounds__(256) void mfma_gemm_kernel(
    const __bf16* __restrict__ A,    // M x 512, K-contiguous
    const __bf16* __restrict__ Bm,   // 512 x 512, K-contiguous
    float* __restrict__ Out,         // M x 512
    const float* __restrict__ U,     // EPI==1 only
    const float* __restrict__ Dv)    // EPI==1 only
{
    __shared__ __bf16 As[128 * 32];
    __shared__ __bf16 Bs[128 * 32];

    const int tid = threadIdx.x;
    const int w  = tid >> 6;
    const int ln = tid & 63;
    const int bm = blockIdx.x;
    const int bn = blockIdx.y;

    floatx4 acc[4][4];
    #pragma unroll
    for (int i = 0; i < 4; ++i)
        #pragma unroll
        for (int j = 0; j < 4; ++j)
            acc[i][j] = (floatx4){0.f, 0.f, 0.f, 0.f};

    const int lr = ln >> 2;            // row within wave's 16
    const int lce = (ln & 3) << 3;     // k-elem offset (0,8,16,24)
    const size_t arow = (size_t)(bm * 128 + w * 16 + lr) * K_DIM;
    const size_t brow = (size_t)(bn * 128 + w * 16 + lr) * K_DIM;

    __bf16* lA0 = As + w * 512;
    __bf16* lA1 = As + 2048 + w * 512;
    __bf16* lB0 = Bs + w * 512;
    __bf16* lB1 = Bs + 2048 + w * 512;

    const int wm = (w >> 1) * 64;
    const int wn = (w & 1) * 64;
    const int fr = ln & 15;
    const int fq = (ln >> 4) * 8;

    for (int kt = 0; kt < K_DIM; kt += 32) {
        __syncthreads();
        gll16(A  + arow + kt + lce,                      lA0);
        gll16(A  + arow + (size_t)64 * K_DIM + kt + lce, lA1);
        gll16(Bm + brow + kt + lce,                      lB0);
        gll16(Bm + brow + (size_t)64 * K_DIM + kt + lce, lB1);
        __syncthreads();

        bf16x8 a[4], b[4];
        #pragma unroll
        for (int mt = 0; mt < 4; ++mt)
            a[mt] = *(bf16x8*)&As[(wm + mt * 16 + fr) * 32 + fq];
        #pragma unroll
        for (int nt = 0; nt < 4; ++nt)
            b[nt] = *(bf16x8*)&Bs[(wn + nt * 16 + fr) * 32 + fq];

        #pragma unroll
        for (int mt = 0; mt < 4; ++mt)
            #pragma unroll
            for (int nt = 0; nt < 4; ++nt)
                acc[mt][nt] = __builtin_amdgcn_mfma_f32_16x16x32_bf16(
                    a[mt], b[nt], acc[mt][nt], 0, 0, 0);
    }

    const int rq = (ln >> 4) * 4;
    #pragma unroll
    for (int mt = 0; mt < 4; ++mt) {
        const int gro = bm * 128 + wm + mt * 16 + rq;
        #pragma unroll
        for (int nt = 0; nt < 4; ++nt) {
            const int gco = bn * 128 + wn + nt * 16 + (ln & 15);
            float dh = (EPI == 1) ? Dv[gco] : 0.f;
            #pragma unroll
            for (int r = 0; r < 4; ++r) {
                const size_t o = (size_t)(gro + r) * 512 + gco;
                if (EPI == 0) {
                    Out[o] = acc[mt][nt][r];
                } else {
                    Out[o] = 2.0f * acc[mt][nt][r] + dh * U[o];
                }
            }
        }
    }
}

// ---------------------------------------------------------------------------
// Chunked scan: x_l = a_l * x_{l-1} + b_l (complex per channel p).
// G2 layout: G2[l*512 + p] = Gre, G2[l*512 + 256 + p] = Gim.
// WRITE_X==0: chunk aggregates (A,b) -> Agg[p*NCHUNK+c] as float4.
// WRITE_X==1: start from Carry[c*P+p], emit bf16 X2.
// ---------------------------------------------------------------------------
template <int WRITE_X>
__global__ __launch_bounds__(256) void scan_chunk_kernel(
    const float* __restrict__ dts,
    const float* __restrict__ Lre_g, const float* __restrict__ Lim_g,
    const float* __restrict__ logstep,
    const float* __restrict__ G2,     // L x 512 fp32
    __bf16* __restrict__ X2,          // L x 512 bf16 (WRITE_X==1)
    float4* __restrict__ Agg,         // P x NCHUNK (WRITE_X==0)
    const float2* __restrict__ Carry) // NCHUNK x P (WRITE_X==1)
{
    const int p = threadIdx.x;
    const int c = blockIdx.x;

    const float lre = Lre_g[p];
    const float lim = Lim_g[p];
    const float stp = __expf(logstep[p]);
    const float inv_den = 1.0f / (lre * lre + lim * lim);

    float Are = 1.0f, Aim = 0.0f;
    float xre, xim;
    if (WRITE_X) {
        float2 cc = Carry[c * P_DIM + p];
        xre = cc.x; xim = cc.y;
    } else {
        xre = 0.0f; xim = 0.0f;
    }

    const int base = c * CHUNK;
    for (int i = 0; i < CHUNK; ++i) {
        const int l = base + i;
        const float d = stp * dts[l];
        const float er = __expf(lre * d);
        float sn, cs;
        __sincosf(lim * d, &sn, &cs);
        const float are = er * cs;
        const float aim = er * sn;
        const float am1 = are - 1.0f;
        const float gr = (am1 * lre + aim * lim) * inv_den;
        const float gi = (aim * lre - am1 * lim) * inv_den;

        const size_t idx = (size_t)l * 512 + p;
        const float ure = G2[idx];
        const float uim = G2[idx + 256];
        const float bre = gr * ure - gi * uim;
        const float bim = gr * uim + gi * ure;

        const float nxre = are * xre - aim * xim + bre;
        const float nxim = are * xim + aim * xre + bim;
        xre = nxre; xim = nxim;

        if (WRITE_X) {
            X2[idx]       = (__bf16)xre;
            X2[idx + 256] = (__bf16)xim;
        } else {
            const float nAre = are * Are - aim * Aim;
            const float nAim = are * Aim + aim * Are;
            Are = nAre; Aim = nAim;
        }
    }

    if (!WRITE_X) {
        Agg[p * NCHUNK + c] = make_float4(Are, Aim, xre, xim);
    }
}

// ---------------------------------------------------------------------------
// Parallel carry scan: one block per channel p, one thread per chunk c.
// Kogge-Stone inclusive scan over 1024 (A,b) pairs in LDS; carry[c] =
// inclusive[c-1].b (exclusive).
// ---------------------------------------------------------------------------
__global__ __launch_bounds__(1024) void carry_kernel(
    const float4* __restrict__ Agg,   // P x NCHUNK
    float2* __restrict__ Carry)       // NCHUNK x P
{
    const int p = blockIdx.x;
    const int c = threadIdx.x;

    __shared__ float sAr[NCHUNK], sAi[NCHUNK], sBr[NCHUNK], sBi[NCHUNK];

    float4 v = Agg[p * NCHUNK + c];
    float ar = v.x, ai = v.y, br = v.z, bi = v.w;
    sAr[c] = ar; sAi[c] = ai; sBr[c] = br; sBi[c] = bi;
    __syncthreads();

    #pragma unroll
    for (int off = 1; off < NCHUNK; off <<= 1) {
        float par, pai, pbr, pbi;
        const bool act = (c >= off);
        if (act) {
            par = sAr[c - off]; pai = sAi[c - off];
            pbr = sBr[c - off]; pbi = sBi[c - off];
        }
        __syncthreads();
        if (act) {
            // combine(prev=i, cur=j): A = Aj*Ai; b = Aj*bi + bj
            const float nbr = ar * pbr - ai * pbi + br;
            const float nbi = ar * pbi + ai * pbr + bi;
            const float nar = ar * par - ai * pai;
            const float nai = ar * pai + ai * par;
            ar = nar; ai = nai; br = nbr; bi = nbi;
            sAr[c] = ar; sAi[c] = ai; sBr[c] = br; sBi[c] = bi;
        }
        __syncthreads();
    }

    float cr = 0.0f, ci = 0.0f;
    if (c > 0) { cr = sBr[c - 1]; ci = sBi[c - 1]; }
    Carry[c * P_DIM + p] = make_float2(cr, ci);
}

extern "C" void kernel_launch(void* const* d_in, const int* in_sizes, int n_in,
                              void* d_out, int out_size, void* d_ws, size_t ws_size,
                              hipStream_t stream) {
    const float* U       = (const float*)d_in[0];
    const float* dts     = (const float*)d_in[1];
    const float* Lre     = (const float*)d_in[2];
    const float* Lim     = (const float*)d_in[3];
    const float* Bre     = (const float*)d_in[4];
    const float* Bim     = (const float*)d_in[5];
    const float* Cre     = (const float*)d_in[6];
    const float* Cim     = (const float*)d_in[7];
    const float* Dv      = (const float*)d_in[8];
    const float* logstep = (const float*)d_in[9];
    float* out = (float*)d_out;

    // workspace carve
    char* ws = (char*)d_ws;
    __bf16* Ubf  = (__bf16*)ws;                              // L x 512 bf16 (32 MB)
    __bf16* X2   = Ubf;                                      // alias: Ubf dead after gemm1
    __bf16* B2   = (__bf16*)(ws + (size_t)L_SEQ * 512 * 2);  // 512x512 bf16
    __bf16* C2   = B2 + 512 * 512;                           // 512x512 bf16
    float4* Agg  = (float4*)(C2 + 512 * 512);                // P x NCHUNK (4 MB)
    float2* Carry = (float2*)(Agg + (size_t)P_DIM * NCHUNK); // NCHUNK x P (2 MB)

    // G2 (fp32 L x 512) lives in d_out until gemm2 overwrites it
    float* G2 = out;

    // conversions
    f2bf_kernel<<<(L_SEQ * H_DIM) / 4 / 256, 256, 0, stream>>>(U, Ubf);
    f2bf_kernel<<<(P_DIM * H_DIM) / 4 / 256, 256, 0, stream>>>(Bre, B2);
    f2bf_kernel<<<(P_DIM * H_DIM) / 4 / 256, 256, 0, stream>>>(Bim, B2 + P_DIM * H_DIM);
    build_c2_kernel<<<H_DIM, 256, 0, stream>>>(Cre, Cim, C2);

    // GEMM1: G2 = Ubf * B2^T  (cols 0..255 = Re, 256..511 = Im)
    dim3 g1(L_SEQ / 128, 4);
    mfma_gemm_kernel<0><<<g1, 256, 0, stream>>>(Ubf, B2, G2, nullptr, nullptr);

    // scan
    scan_chunk_kernel<0><<<NCHUNK, 256, 0, stream>>>(
        dts, Lre, Lim, logstep, G2, nullptr, Agg, nullptr);
    carry_kernel<<<P_DIM, NCHUNK, 0, stream>>>(Agg, Carry);
    scan_chunk_kernel<1><<<NCHUNK, 256, 0, stream>>>(
        dts, Lre, Lim, logstep, G2, X2, nullptr, Carry);

    // GEMM2: out = 2 * X2 * C2^T + D*u
    dim3 g2(L_SEQ / 128, 4);
    mfma_gemm_kernel<1><<<g2, 256, 0, stream>>>(X2, C2, out, U, Dv);
}

// Round 4
// 232.229 us; speedup vs baseline: 2.8368x; 1.0525x over previous
//
#include <hip/hip_runtime.h>
#include <math.h>

#define L_SEQ 32768
#define H_DIM 512
#define P_DIM 256
#define K_DIM 512
#define CHUNK 32
#define NCHUNK (L_SEQ / CHUNK)   // 1024

typedef __bf16 bf16x8 __attribute__((ext_vector_type(8)));
typedef float floatx4 __attribute__((ext_vector_type(4)));

__device__ __forceinline__ void gll16(const void* g, void* l) {
    __builtin_amdgcn_global_load_lds(
        (__attribute__((address_space(1))) void*)(g),
        (__attribute__((address_space(3))) void*)(l), 16, 0, 0);
}

// B2[2p, h] = Bre[p,h]; B2[2p+1, h] = Bim[p,h]   (512 x 512 bf16)
__global__ __launch_bounds__(512) void build_b2_kernel(
    const float* __restrict__ Bre, const float* __restrict__ Bim,
    __bf16* __restrict__ B2)
{
    const int p = blockIdx.x;     // 0..255
    const int h = threadIdx.x;    // 0..511
    B2[(2 * p) * 512 + h]     = (__bf16)Bre[p * H_DIM + h];
    B2[(2 * p + 1) * 512 + h] = (__bf16)Bim[p * H_DIM + h];
}

// C2[h, 2p] = Cre[h,p]; C2[h, 2p+1] = -Cim[h,p]   (512 x 512 bf16)
__global__ __launch_bounds__(256) void build_c2_kernel(
    const float* __restrict__ Cre, const float* __restrict__ Cim,
    __bf16* __restrict__ C2)
{
    const int h = blockIdx.x;     // 0..511
    const int p = threadIdx.x;    // 0..255
    C2[h * 512 + 2 * p]     = (__bf16)Cre[h * P_DIM + p];
    C2[h * 512 + 2 * p + 1] = (__bf16)(-Cim[h * P_DIM + p]);
}

// ---------------------------------------------------------------------------
// GEMM1: G2[l,j] = sum_h U[l,h]*B2[j,h].  A is fp32 (staged raw, cvt at frag
// read); B bf16; out bf16 interleaved. BM=BN=128, BK=32, 4 waves.
// ---------------------------------------------------------------------------
__global__ __launch_bounds__(256) void gemm1_kernel(
    const float* __restrict__ A,     // L x 512 fp32 (U)
    const __bf16* __restrict__ Bm,   // 512 x 512 bf16 (B2)
    __bf16* __restrict__ Out)        // L x 512 bf16 (G2)
{
    __shared__ float  Asf[128 * 32];   // 16 KB
    __shared__ __bf16 Bs [128 * 32];   // 8 KB

    const int tid = threadIdx.x;
    const int w  = tid >> 6;
    const int ln = tid & 63;
    const int bm = blockIdx.x;
    const int bn = blockIdx.y;

    floatx4 acc[4][4];
    #pragma unroll
    for (int i = 0; i < 4; ++i)
        #pragma unroll
        for (int j = 0; j < 4; ++j)
            acc[i][j] = (floatx4){0.f, 0.f, 0.f, 0.f};

    // A staging: issue q covers rows q*32 + w*8 .. +8; lane row=ln>>3, col=(ln&7)*4 floats
    const int a_r = ln >> 3;
    const int a_c = (ln & 7) << 2;
    // B staging: chunk rows w*16 (and +64); lane row=ln>>2, col=(ln&3)*8 bf16
    const int b_r = ln >> 2;
    const int b_c = (ln & 3) << 3;
    const size_t brow = (size_t)(bn * 128 + w * 16 + b_r) * K_DIM;

    float*  lA[4];
    size_t  gAr[4];
    #pragma unroll
    for (int q = 0; q < 4; ++q) {
        lA[q] = Asf + (q * 32 + w * 8) * 32;
        gAr[q] = (size_t)(bm * 128 + q * 32 + w * 8 + a_r) * K_DIM;
    }
    __bf16* lB0 = Bs + w * 512;
    __bf16* lB1 = Bs + 2048 + w * 512;

    const int wm = (w >> 1) * 64;
    const int wn = (w & 1) * 64;
    const int fr = ln & 15;
    const int fq = (ln >> 4) * 8;

    for (int kt = 0; kt < K_DIM; kt += 32) {
        __syncthreads();
        #pragma unroll
        for (int q = 0; q < 4; ++q)
            gll16(A + gAr[q] + kt + a_c, lA[q]);
        gll16(Bm + brow + kt + b_c,                      lB0);
        gll16(Bm + brow + (size_t)64 * K_DIM + kt + b_c, lB1);
        __syncthreads();

        bf16x8 a[4], b[4];
        #pragma unroll
        for (int mt = 0; mt < 4; ++mt) {
            floatx4 a0 = *(floatx4*)&Asf[(wm + mt * 16 + fr) * 32 + fq];
            floatx4 a1 = *(floatx4*)&Asf[(wm + mt * 16 + fr) * 32 + fq + 4];
            #pragma unroll
            for (int r = 0; r < 4; ++r) {
                a[mt][r]     = (__bf16)a0[r];
                a[mt][4 + r] = (__bf16)a1[r];
            }
        }
        #pragma unroll
        for (int nt = 0; nt < 4; ++nt)
            b[nt] = *(bf16x8*)&Bs[(wn + nt * 16 + fr) * 32 + fq];

        #pragma unroll
        for (int mt = 0; mt < 4; ++mt)
            #pragma unroll
            for (int nt = 0; nt < 4; ++nt)
                acc[mt][nt] = __builtin_amdgcn_mfma_f32_16x16x32_bf16(
                    a[mt], b[nt], acc[mt][nt], 0, 0, 0);
    }

    const int rq = (ln >> 4) * 4;
    #pragma unroll
    for (int mt = 0; mt < 4; ++mt) {
        const int gro = bm * 128 + wm + mt * 16 + rq;
        #pragma unroll
        for (int nt = 0; nt < 4; ++nt) {
            const int gco = bn * 128 + wn + nt * 16 + (ln & 15);
            #pragma unroll
            for (int r = 0; r < 4; ++r)
                Out[(size_t)(gro + r) * 512 + gco] = (__bf16)acc[mt][nt][r];
        }
    }
}

// ---------------------------------------------------------------------------
// GEMM2: out = 2 * X2 * C2^T + D*u.  bf16 A/B, fp32 out. (m97 structure)
// ---------------------------------------------------------------------------
__global__ __launch_bounds__(256) void gemm2_kernel(
    const __bf16* __restrict__ A,    // L x 512 bf16 (X2)
    const __bf16* __restrict__ Bm,   // 512 x 512 bf16 (C2)
    float* __restrict__ Out,         // L x 512 fp32
    const float* __restrict__ U,
    const float* __restrict__ Dv)
{
    __shared__ __bf16 As[128 * 32];
    __shared__ __bf16 Bs[128 * 32];

    const int tid = threadIdx.x;
    const int w  = tid >> 6;
    const int ln = tid & 63;
    const int bm = blockIdx.x;
    const int bn = blockIdx.y;

    floatx4 acc[4][4];
    #pragma unroll
    for (int i = 0; i < 4; ++i)
        #pragma unroll
        for (int j = 0; j < 4; ++j)
            acc[i][j] = (floatx4){0.f, 0.f, 0.f, 0.f};

    const int lr = ln >> 2;
    const int lce = (ln & 3) << 3;
    const size_t arow = (size_t)(bm * 128 + w * 16 + lr) * K_DIM;
    const size_t brow = (size_t)(bn * 128 + w * 16 + lr) * K_DIM;

    __bf16* lA0 = As + w * 512;
    __bf16* lA1 = As + 2048 + w * 512;
    __bf16* lB0 = Bs + w * 512;
    __bf16* lB1 = Bs + 2048 + w * 512;

    const int wm = (w >> 1) * 64;
    const int wn = (w & 1) * 64;
    const int fr = ln & 15;
    const int fq = (ln >> 4) * 8;

    for (int kt = 0; kt < K_DIM; kt += 32) {
        __syncthreads();
        gll16(A  + arow + kt + lce,                      lA0);
        gll16(A  + arow + (size_t)64 * K_DIM + kt + lce, lA1);
        gll16(Bm + brow + kt + lce,                      lB0);
        gll16(Bm + brow + (size_t)64 * K_DIM + kt + lce, lB1);
        __syncthreads();

        bf16x8 a[4], b[4];
        #pragma unroll
        for (int mt = 0; mt < 4; ++mt)
            a[mt] = *(bf16x8*)&As[(wm + mt * 16 + fr) * 32 + fq];
        #pragma unroll
        for (int nt = 0; nt < 4; ++nt)
            b[nt] = *(bf16x8*)&Bs[(wn + nt * 16 + fr) * 32 + fq];

        #pragma unroll
        for (int mt = 0; mt < 4; ++mt)
            #pragma unroll
            for (int nt = 0; nt < 4; ++nt)
                acc[mt][nt] = __builtin_amdgcn_mfma_f32_16x16x32_bf16(
                    a[mt], b[nt], acc[mt][nt], 0, 0, 0);
    }

    const int rq = (ln >> 4) * 4;
    #pragma unroll
    for (int mt = 0; mt < 4; ++mt) {
        const int gro = bm * 128 + wm + mt * 16 + rq;
        #pragma unroll
        for (int nt = 0; nt < 4; ++nt) {
            const int gco = bn * 128 + wn + nt * 16 + (ln & 15);
            const float dh = Dv[gco];
            #pragma unroll
            for (int r = 0; r < 4; ++r) {
                const size_t o = (size_t)(gro + r) * 512 + gco;
                Out[o] = 2.0f * acc[mt][nt][r] + dh * U[o];
            }
        }
    }
}

// ---------------------------------------------------------------------------
// Chunked scan with register prefetch. G2 interleaved bf16: uint per (l,p).
// WRITE_X==0: aggregates -> Agg[p*NCHUNK+c]. WRITE_X==1: carry -> X in place.
// ---------------------------------------------------------------------------
template <int WRITE_X>
__global__ __launch_bounds__(256) void scan_chunk_kernel(
    const float* __restrict__ dts,
    const float* __restrict__ Lre_g, const float* __restrict__ Lim_g,
    const float* __restrict__ logstep,
    unsigned int* __restrict__ G2u,   // L x 256 uints (bf16 re|im)
    float4* __restrict__ Agg,
    const float2* __restrict__ Carry)
{
    const int p = threadIdx.x;
    const int c = blockIdx.x;
    const int base = c * CHUNK;

    // prefetch: all loads issued before the serial recurrence
    unsigned int g[CHUNK];
    float dt[CHUNK];
    #pragma unroll
    for (int i = 0; i < CHUNK; ++i)
        g[i] = G2u[(size_t)(base + i) * 256 + p];
    #pragma unroll
    for (int i = 0; i < CHUNK; ++i)
        dt[i] = dts[base + i];

    const float lre = Lre_g[p];
    const float lim = Lim_g[p];
    const float stp = __expf(logstep[p]);
    const float inv_den = 1.0f / (lre * lre + lim * lim);

    float Are = 1.0f, Aim = 0.0f;
    float xre, xim;
    if (WRITE_X) {
        float2 cc = Carry[c * P_DIM + p];
        xre = cc.x; xim = cc.y;
    } else {
        xre = 0.0f; xim = 0.0f;
    }

    #pragma unroll
    for (int i = 0; i < CHUNK; ++i) {
        const float d = stp * dt[i];
        const float er = __expf(lre * d);
        float sn, cs;
        __sincosf(lim * d, &sn, &cs);
        const float are = er * cs;
        const float aim = er * sn;
        const float am1 = are - 1.0f;
        const float gr = (am1 * lre + aim * lim) * inv_den;
        const float gi = (aim * lre - am1 * lim) * inv_den;

        const float ure = __uint_as_float(g[i] << 16);
        const float uim = __uint_as_float(g[i] & 0xffff0000u);
        const float bre = gr * ure - gi * uim;
        const float bim = gr * uim + gi * ure;

        const float nxre = are * xre - aim * xim + bre;
        const float nxim = are * xim + aim * xre + bim;
        xre = nxre; xim = nxim;

        if (WRITE_X) {
            __bf16 xr = (__bf16)xre;
            __bf16 xi = (__bf16)xim;
            unsigned int o = (unsigned int)*(unsigned short*)&xr |
                             ((unsigned int)*(unsigned short*)&xi << 16);
            G2u[(size_t)(base + i) * 256 + p] = o;
        } else {
            const float nAre = are * Are - aim * Aim;
            const float nAim = are * Aim + aim * Are;
            Are = nAre; Aim = nAim;
        }
    }

    if (!WRITE_X)
        Agg[p * NCHUNK + c] = make_float4(Are, Aim, xre, xim);
}

// ---------------------------------------------------------------------------
// Kogge-Stone carry scan: one block per channel, one thread per chunk.
// ---------------------------------------------------------------------------
__global__ __launch_bounds__(1024) void carry_kernel(
    const float4* __restrict__ Agg,   // P x NCHUNK
    float2* __restrict__ Carry)       // NCHUNK x P
{
    const int p = blockIdx.x;
    const int c = threadIdx.x;

    __shared__ float sAr[NCHUNK], sAi[NCHUNK], sBr[NCHUNK], sBi[NCHUNK];

    float4 v = Agg[p * NCHUNK + c];
    float ar = v.x, ai = v.y, br = v.z, bi = v.w;
    sAr[c] = ar; sAi[c] = ai; sBr[c] = br; sBi[c] = bi;
    __syncthreads();

    #pragma unroll
    for (int off = 1; off < NCHUNK; off <<= 1) {
        float par, pai, pbr, pbi;
        const bool act = (c >= off);
        if (act) {
            par = sAr[c - off]; pai = sAi[c - off];
            pbr = sBr[c - off]; pbi = sBi[c - off];
        }
        __syncthreads();
        if (act) {
            const float nbr = ar * pbr - ai * pbi + br;
            const float nbi = ar * pbi + ai * pbr + bi;
            const float nar = ar * par - ai * pai;
            const float nai = ar * pai + ai * par;
            ar = nar; ai = nai; br = nbr; bi = nbi;
            sAr[c] = ar; sAi[c] = ai; sBr[c] = br; sBi[c] = bi;
        }
        __syncthreads();
    }

    float cr = 0.0f, ci = 0.0f;
    if (c > 0) { cr = sBr[c - 1]; ci = sBi[c - 1]; }
    Carry[c * P_DIM + p] = make_float2(cr, ci);
}

extern "C" void kernel_launch(void* const* d_in, const int* in_sizes, int n_in,
                              void* d_out, int out_size, void* d_ws, size_t ws_size,
                              hipStream_t stream) {
    const float* U       = (const float*)d_in[0];
    const float* dts     = (const float*)d_in[1];
    const float* Lre     = (const float*)d_in[2];
    const float* Lim     = (const float*)d_in[3];
    const float* Bre     = (const float*)d_in[4];
    const float* Bim     = (const float*)d_in[5];
    const float* Cre     = (const float*)d_in[6];
    const float* Cim     = (const float*)d_in[7];
    const float* Dv      = (const float*)d_in[8];
    const float* logstep = (const float*)d_in[9];
    float* out = (float*)d_out;

    // workspace: G2 (32 MB) + B2 (.5) + C2 (.5) + Agg (4) + Carry (2) = 39 MB
    char* ws = (char*)d_ws;
    __bf16* G2 = (__bf16*)ws;                                 // L x 512 bf16
    __bf16* B2 = (__bf16*)(ws + (size_t)L_SEQ * 512 * 2);
    __bf16* C2 = B2 + 512 * 512;
    float4* Agg = (float4*)(C2 + 512 * 512);
    float2* Carry = (float2*)(Agg + (size_t)P_DIM * NCHUNK);

    build_b2_kernel<<<P_DIM, 512, 0, stream>>>(Bre, Bim, B2);
    build_c2_kernel<<<H_DIM, 256, 0, stream>>>(Cre, Cim, C2);

    dim3 g1(L_SEQ / 128, 4);
    gemm1_kernel<<<g1, 256, 0, stream>>>(U, B2, G2);

    unsigned int* G2u = (unsigned int*)G2;
    scan_chunk_kernel<0><<<NCHUNK, 256, 0, stream>>>(
        dts, Lre, Lim, logstep, G2u, Agg, nullptr);
    carry_kernel<<<P_DIM, NCHUNK, 0, stream>>>(Agg, Carry);
    scan_chunk_kernel<1><<<NCHUNK, 256, 0, stream>>>(
        dts, Lre, Lim, logstep, G2u, nullptr, Carry);

    dim3 g2(L_SEQ / 128, 4);
    gemm2_kernel<<<g2, 256, 0, stream>>>(G2, C2, out, U, Dv);
}